// Round 19
// baseline (131.061 us; speedup 1.0000x reference)
//
#include <hip/hip_runtime.h>
#include <hip/hip_bf16.h>

#define B_TOTAL 65536
#define NR 4
#define VD 100
#define HD 200
#define DK 32
#define MH 128
#define RD 64

typedef __attribute__((ext_vector_type(8))) short bf16x8;
typedef __attribute__((ext_vector_type(4))) float f32x4;

static __device__ inline unsigned short f2bf(float x) {
    __hip_bfloat16 h = __float2bfloat16(x);
    return __builtin_bit_cast(unsigned short, h);
}

// ---- workspace layout (bytes) ---- total 374,784
#define WS_GD    0         // 2400*8 = 19200  (fp64 G for fixup, layout j*8+p)
#define WS_GSC   19200     // 5632*2 = 11264  (bf16 score-G MFMA B-fragment, K=352)
#define WS_W1F   30720     // 114688*2 = 229376 (remapped: c<100->k'=c, 112<=c<212->k'=c-12)
#define WS_W2F   260096    // 57344*2 = 114688

// ---------------- kernel 0a: Gd (fp64 fixup table) + Gsc (bf16 fragment) ----------------
__global__ __launch_bounds__(256) void k0_prep(
    const float* __restrict__ rule_emb, const float* __restrict__ Wq,
    const float* __restrict__ bq, const float* __restrict__ Wk,
    double* __restrict__ Gd, unsigned short* __restrict__ Gsc)
{
    int tid = threadIdx.x;
    __shared__ double readS[NR * DK];
    if (tid < NR * DK) {
        int r = tid >> 5, k = tid & 31;
        double a = (double)bq[k];
        for (int d = 0; d < RD; ++d)
            a += (double)rule_emb[r * RD + d] * (double)Wq[d * DK + k];
        readS[tid] = a;
    }
    __syncthreads();

    // fp64 fixup table: Gd[j*8+p], j = s*100+dd
    for (int idx = tid; idx < 2400; idx += 256) {
        int j = idx >> 3, p = idx & 7;
        int rr = p >> 1, vv = p & 1;
        int s = j / 100, dd = j - s * 100;
        double g = 0.0;
        if (s == vv) {
            for (int kk = 0; kk < DK; ++kk)
                g += (double)Wk[(vv * HD + dd) * DK + kk] * readS[rr * DK + kk];
        } else if (s == 2) {
            for (int kk = 0; kk < DK; ++kk)
                g += (double)Wk[(vv * HD + 100 + dd) * DK + kk] * readS[rr * DK + kk];
        }
        Gd[idx] = g;
    }

    // bf16 score-G fragment: K=352, X cols = [seg0 112 | seg1 112 | seg2 112 | pad16]
    // lane l: col p = l&15 (p>=8 zero), k = ks*32 + (l>>4)*8 + j
    for (int i = tid; i < 11 * 512; i += 256) {
        int ks = i >> 9, l = (i >> 3) & 63, j = i & 7;
        int k = ks * 32 + ((l >> 4) << 3) + j;
        int p = l & 15;
        double g = 0.0;
        if (p < 8 && k < 336) {
            int seg = k / 112, dd = k - seg * 112;
            if (dd < 100) {
                int rr = p >> 1, vv = p & 1;
                int wrow = -1;
                if (seg == vv)      wrow = vv * HD + dd;
                else if (seg == 2)  wrow = vv * HD + 100 + dd;
                if (wrow >= 0)
                    for (int kk = 0; kk < DK; ++kk)
                        g += (double)Wk[wrow * DK + kk] * readS[rr * DK + kk];
            }
        }
        Gsc[i] = f2bf((float)g);
    }
}

// ---------------- kernel 0b: W1/W2 -> bf16 MFMA B-fragment layout ----------------
// W1f: fragment col k in [0,224) maps to W1 row k' : k<100 -> k ; 112<=k<212 -> k-12 ; else 0.
__global__ __launch_bounds__(256) void k0_wfrag(
    const float* __restrict__ W1, const float* __restrict__ W2,
    unsigned short* __restrict__ W1f, unsigned short* __restrict__ W2f)
{
    int i = blockIdx.x * 256 + threadIdx.x;
    if (i < 114688) {
        int r = i / 28672, rem = i % 28672;
        int ks = rem / 4096, rem2 = rem % 4096;
        int n = rem2 >> 9, l = (rem2 >> 3) & 63, j = rem2 & 7;
        int k = ks * 32 + ((l >> 4) << 3) + j;
        int c = n * 16 + (l & 15);
        int kp = (k < 100) ? k : (k >= 112 && k < 212) ? (k - 12) : -1;
        float v = (kp >= 0) ? W1[((size_t)r * HD + kp) * MH + c] : 0.f;
        W1f[i] = f2bf(v);
    } else if (i < 114688 + 57344) {
        int t = i - 114688;
        int r = t / 14336, rem = t % 14336;
        int ks = rem / 3584, rem2 = rem % 3584;
        int n = rem2 >> 9, l = (rem2 >> 3) & 63, j = rem2 & 7;
        int k = ks * 32 + ((l >> 4) << 3) + j;
        int c = n * 16 + (l & 15);
        float v = (c < VD) ? W2[((size_t)r * MH + k) * VD + c] : 0.f;
        W2f[t] = f2bf(v);
    }
}

// ---------------- fused main: stage once -> bf16-MFMA scores -> fixup -> 4-rule MLP ----------------
// 64 linear rows/block, 1024 blocks, ~64KB LDS -> 2 blocks/CU (k2-like overlap).
// Scores: 11 MFMAs/wave (K=352). Gap<0.5 rows (err bound ~0.023) -> fp64 fixup
// from global f32 (seed-0 data shown across 6 passing runs to have no ties
// below ~1e-4 -> fixup argmax == fp32-reference argmax).
// MLP: all 4 rules on the staged X; A-operand v-dependent addressing (each
// 8-chunk within one 112-span); store rows where rsel==r. No buckets/gather.
__global__ __launch_bounds__(256) void k_main(
    const float* __restrict__ hidden, const unsigned short* __restrict__ Gsc,
    const double* __restrict__ Gd, const unsigned short* __restrict__ W1f,
    const unsigned short* __restrict__ W2f, float* __restrict__ out)
{
    __shared__ __align__(16) unsigned short hb[64 * 360];  // 46080 B
    __shared__ __align__(16) unsigned short c1[64 * 136];  // 17408 B
    __shared__ int vr[64], rs[64];
    __shared__ int flagl[64];
    __shared__ int nflag;

    int tid = threadIdx.x;
    int rowbase = blockIdx.x * 64;
    if (tid == 0) nflag = 0;

    // ---- stage: 4800 float4, coalesced; bf16 into [seg0|seg1|seg2] stride 360 ----
    const float4* src4 = (const float4*)(hidden + (size_t)rowbase * 300);
#pragma unroll
    for (int kk = 0; kk < 19; ++kk) {
        int idx = tid + kk * 256;
        if (idx < 4800) {
            int row = idx / 75, c4 = idx - row * 75;
            float4 v = src4[idx];
            int cg = c4 * 4, seg = cg / 100, dd = cg - seg * 100;
            ushort4 o;
            o.x = f2bf(v.x); o.y = f2bf(v.y); o.z = f2bf(v.z); o.w = f2bf(v.w);
            *(ushort4*)&hb[row * 360 + seg * 112 + dd] = o;
        }
    }
    // zero pads: [100,112) [212,224) [324,360) per row = 15 ushort4
    for (int i = tid; i < 960; i += 256) {
        int row = i / 15, t = i - (i / 15) * 15;
        int off = (t < 3) ? (100 + t * 4) : (t < 6) ? (212 + (t - 3) * 4) : (324 + (t - 6) * 4);
        ushort4 z; z.x = z.y = z.z = z.w = 0;
        *(ushort4*)&hb[row * 360 + off] = z;
    }
    __syncthreads();

    int wave = tid >> 6, lane = tid & 63;
    int lr = lane & 15, lk = lane >> 4;
    int wrow0 = wave * 16;

    // ---- scores: 11 x mfma_16x16x32_bf16, then 16-lane top-2 butterfly ----
    {
        f32x4 sacc = (f32x4){0.f, 0.f, 0.f, 0.f};
#pragma unroll
        for (int ks = 0; ks < 11; ++ks) {
            bf16x8 a = *(const bf16x8*)&hb[(wrow0 + lr) * 360 + ks * 32 + lk * 8];
            bf16x8 g = *(const bf16x8*)&Gsc[(size_t)ks * 512 + lane * 8];
            sacc = __builtin_amdgcn_mfma_f32_16x16x32_bf16(a, g, sacc, 0, 0, 0);
        }
#pragma unroll
        for (int j = 0; j < 4; ++j) {
            float v1 = (lr < 8) ? sacc[j] : -3.4e38f;
            int i1 = lr;
            float v2 = -3.4e38f;
#pragma unroll
            for (int m = 1; m <= 8; m <<= 1) {
                float ov1 = __shfl_xor(v1, m);
                int oi1 = __shfl_xor(i1, m);
                float ov2 = __shfl_xor(v2, m);
                float nv2 = fmaxf(fminf(v1, ov1), fmaxf(v2, ov2));
                if (ov1 > v1 || (ov1 == v1 && oi1 < i1)) { v1 = ov1; i1 = oi1; }
                v2 = nv2;
            }
            if (lr == 0) {
                int row = wrow0 + lk * 4 + j;       // proven C layout: row=(l>>4)*4+j
                vr[row] = i1 & 1; rs[row] = i1 >> 1;
                if (v1 - v2 < 0.5f) { int s = atomicAdd(&nflag, 1); flagl[s] = row; }
            }
        }
    }
    __syncthreads();

    // ---- fp64 fixup for flagged rows (one wave per row) ----
    for (int f = wave; f < nflag; f += 4) {
        int row = flagl[f];
        const float* hr = hidden + (size_t)(rowbase + row) * 300;
        double a8[8];
#pragma unroll
        for (int p = 0; p < 8; ++p) a8[p] = 0.0;
        for (int e = lane; e < 300; e += 64) {
            double x = (double)hr[e];
#pragma unroll
            for (int p = 0; p < 8; ++p) a8[p] = fma(x, Gd[e * 8 + p], a8[p]);
        }
#pragma unroll
        for (int m = 1; m < 64; m <<= 1)
#pragma unroll
            for (int p = 0; p < 8; ++p) a8[p] += __shfl_xor(a8[p], m);
        if (lane == 0) {
            double bv = a8[0]; int best = 0;
#pragma unroll
            for (int p = 1; p < 8; ++p) if (a8[p] > bv) { bv = a8[p]; best = p; }
            vr[row] = best & 1; rs[row] = best >> 1;
        }
    }
    __syncthreads();

    // ---- MLP: 4 rules on staged X; v-dependent A addressing; masked store ----
    int myv = 0;
    {
        myv = vr[wrow0 + lr];
    }
    for (int r = 0; r < NR; ++r) {
        const unsigned short* W1f_r = W1f + (size_t)r * 28672;
        f32x4 acc1[8];
#pragma unroll
        for (int n = 0; n < 8; ++n) acc1[n] = (f32x4){0.f, 0.f, 0.f, 0.f};

#pragma unroll
        for (int ks = 0; ks < 7; ++ks) {
            int c0 = ks * 32 + lk * 8;
            int addr = (c0 < 112) ? ((wrow0 + lr) * 360 + myv * 112 + c0)
                                  : ((wrow0 + lr) * 360 + (1 - myv) * 112 + (c0 - 112));
            bf16x8 a0 = *(const bf16x8*)&hb[addr];
#pragma unroll
            for (int n = 0; n < 8; ++n) {
                bf16x8 bfr = *(const bf16x8*)&W1f_r[(size_t)(ks * 8 + n) * 512 + lane * 8];
                acc1[n] = __builtin_amdgcn_mfma_f32_16x16x32_bf16(a0, bfr, acc1[n], 0, 0, 0);
            }
        }

        // relu -> c1 (wave-local rows; no cross-wave hazard, no barrier needed)
#pragma unroll
        for (int n = 0; n < 8; ++n)
#pragma unroll
            for (int j = 0; j < 4; ++j) {
                float v = fmaxf(acc1[n][j], 0.f);
                c1[(wrow0 + lk * 4 + j) * 136 + n * 16 + lr] = f2bf(v);
            }

        const unsigned short* W2f_r = W2f + (size_t)r * 14336;
        f32x4 acc2[7];
#pragma unroll
        for (int n = 0; n < 7; ++n) acc2[n] = (f32x4){0.f, 0.f, 0.f, 0.f};

#pragma unroll
        for (int ks = 0; ks < 4; ++ks) {
            bf16x8 a0 = *(const bf16x8*)&c1[(wrow0 + lr) * 136 + ks * 32 + lk * 8];
#pragma unroll
            for (int n = 0; n < 7; ++n) {
                bf16x8 bfr = *(const bf16x8*)&W2f_r[(size_t)(ks * 7 + n) * 512 + lane * 8];
                acc2[n] = __builtin_amdgcn_mfma_f32_16x16x32_bf16(a0, bfr, acc2[n], 0, 0, 0);
            }
        }

#pragma unroll
        for (int n = 0; n < 7; ++n) {
            int col = n * 16 + lr;
            if (col < VD) {
#pragma unroll
                for (int j = 0; j < 4; ++j) {
                    int e = wrow0 + lk * 4 + j;
                    if (rs[e] == r)
                        out[(size_t)(rowbase + e) * VD + col] = acc2[n][j];
                }
            }
        }
    }
}

extern "C" void kernel_launch(void* const* d_in, const int* in_sizes, int n_in,
                              void* d_out, int out_size, void* d_ws, size_t ws_size,
                              hipStream_t stream) {
    (void)in_sizes; (void)n_in; (void)out_size; (void)ws_size;
    const float* hidden   = (const float*)d_in[0];
    const float* rule_emb = (const float*)d_in[1];
    const float* Wq       = (const float*)d_in[2];
    const float* bq       = (const float*)d_in[3];
    const float* Wk       = (const float*)d_in[4];
    const float* W1       = (const float*)d_in[5];
    const float* W2       = (const float*)d_in[6];
    float* out = (float*)d_out;

    char* ws = (char*)d_ws;
    double* Gd            = (double*)(ws + WS_GD);
    unsigned short* Gsc   = (unsigned short*)(ws + WS_GSC);
    unsigned short* W1f   = (unsigned short*)(ws + WS_W1F);
    unsigned short* W2f   = (unsigned short*)(ws + WS_W2F);

    k0_prep<<<1, 256, 0, stream>>>(rule_emb, Wq, bq, Wk, Gd, Gsc);
    k0_wfrag<<<672, 256, 0, stream>>>(W1, W2, W1f, W2f);
    k_main<<<1024, 256, 0, stream>>>(hidden, Gsc, Gd, W1f, W2f, out);
}

// Round 20
// 117.337 us; speedup vs baseline: 1.1170x; 1.1170x over previous
//
#include <hip/hip_runtime.h>
#include <hip/hip_bf16.h>

#define B_TOTAL 65536
#define NR 4
#define VD 100
#define HD 200
#define DK 32
#define MH 128
#define RD 64

typedef __attribute__((ext_vector_type(8))) short bf16x8;
typedef __attribute__((ext_vector_type(4))) float f32x4;

static __device__ inline unsigned short f2bf(float x) {
    __hip_bfloat16 h = __float2bfloat16(x);
    return __builtin_bit_cast(unsigned short, h);
}

// ---- workspace layout (bytes) ---- total 964,608 (< 1.02 MB proven in R1)
#define WS_GD    0         // 2400*8 = 19200  (fp64 G for fixup, layout j*8+p)
#define WS_GSC   19200     // 5632*2 = 11264  (bf16 score-G MFMA B-fragment, K=352)
#define WS_CNT   30720     // 16
#define WS_LIST  31232     // 4*65536*2 = 524288
#define WS_VB    555520    // 65536
#define WS_W1F   621056    // 229376
#define WS_W2F   850432    // 114688

// ---------------- kernel 0a: Gd (fp64 fixup) + Gsc (bf16 score fragment) + zero cnt ----------------
__global__ __launch_bounds__(256) void k0_prep(
    const float* __restrict__ rule_emb, const float* __restrict__ Wq,
    const float* __restrict__ bq, const float* __restrict__ Wk,
    double* __restrict__ Gd, unsigned short* __restrict__ Gsc,
    int* __restrict__ cnt)
{
    int tid = threadIdx.x;
    if (tid < NR) cnt[tid] = 0;

    __shared__ double readS[NR * DK];
    if (tid < NR * DK) {
        int r = tid >> 5, k = tid & 31;
        double a = (double)bq[k];
        for (int d = 0; d < RD; ++d)
            a += (double)rule_emb[r * RD + d] * (double)Wq[d * DK + k];
        readS[tid] = a;
    }
    __syncthreads();

    // fp64 fixup table: Gd[j*8+p], j = s*100+dd
    for (int idx = tid; idx < 2400; idx += 256) {
        int j = idx >> 3, p = idx & 7;
        int rr = p >> 1, vv = p & 1;
        int s = j / 100, dd = j - s * 100;
        double g = 0.0;
        if (s == vv) {
            for (int kk = 0; kk < DK; ++kk)
                g += (double)Wk[(vv * HD + dd) * DK + kk] * readS[rr * DK + kk];
        } else if (s == 2) {
            for (int kk = 0; kk < DK; ++kk)
                g += (double)Wk[(vv * HD + 100 + dd) * DK + kk] * readS[rr * DK + kk];
        }
        Gd[idx] = g;
    }

    // bf16 score-G fragment: K=352, X cols = [seg0 112 | seg1 112 | seg2 112 | pad16]
    // lane l: col p = l&15 (p>=8 zero), k = ks*32 + (l>>4)*8 + j   [R19-proven]
    for (int i = tid; i < 11 * 512; i += 256) {
        int ks = i >> 9, l = (i >> 3) & 63, j = i & 7;
        int k = ks * 32 + ((l >> 4) << 3) + j;
        int p = l & 15;
        double g = 0.0;
        if (p < 8 && k < 336) {
            int seg = k / 112, dd = k - seg * 112;
            if (dd < 100) {
                int rr = p >> 1, vv = p & 1;
                int wrow = -1;
                if (seg == vv)      wrow = vv * HD + dd;
                else if (seg == 2)  wrow = vv * HD + 100 + dd;
                if (wrow >= 0)
                    for (int kk = 0; kk < DK; ++kk)
                        g += (double)Wk[wrow * DK + kk] * readS[rr * DK + kk];
            }
        }
        Gsc[i] = f2bf((float)g);
    }
}

// ---------------- kernel 0b: W1/W2 -> bf16 MFMA B-fragment layout (R18-proven) ----------------
__global__ __launch_bounds__(256) void k0_wfrag(
    const float* __restrict__ W1, const float* __restrict__ W2,
    unsigned short* __restrict__ W1f, unsigned short* __restrict__ W2f)
{
    int i = blockIdx.x * 256 + threadIdx.x;
    if (i < 114688) {
        int r = i / 28672, rem = i % 28672;
        int ks = rem / 4096, rem2 = rem % 4096;
        int n = rem2 >> 9, l = (rem2 >> 3) & 63, j = rem2 & 7;
        int k = ks * 32 + ((l >> 4) << 3) + j;
        int c = n * 16 + (l & 15);
        float v = (k < HD) ? W1[((size_t)r * HD + k) * MH + c] : 0.f;
        W1f[i] = f2bf(v);
    } else if (i < 114688 + 57344) {
        int t = i - 114688;
        int r = t / 14336, rem = t % 14336;
        int ks = rem / 3584, rem2 = rem % 3584;
        int n = rem2 >> 9, l = (rem2 >> 3) & 63, j = rem2 & 7;
        int k = ks * 32 + ((l >> 4) << 3) + j;
        int c = n * 16 + (l & 15);
        float v = (c < VD) ? W2[((size_t)r * MH + k) * VD + c] : 0.f;
        W2f[t] = f2bf(v);
    }
}

// ---------------- kernel 1: MFMA selection (R19-proven machinery) + bucket compaction ----------------
// 64 linear rows/block, 1024 blocks, 47KB LDS -> 3 blocks/CU.
// Stage bf16 [seg0|seg1|seg2] stride 360 -> 11 x mfma_16x16x32_bf16 scores ->
// 16-lane top-2 butterfly -> gap<0.5 rows get fp64 fixup from global f32
// (R19 PASSED: this selection == fp32-reference argmax exactly) -> proven
// bucket-atomic compaction (list16 + vbyte) for the bucketed MLP.
// R19's regression was the FUSED 4x MLP, not this machinery -- split it out.
__global__ __launch_bounds__(256) void k1_select(
    const float* __restrict__ hidden, const unsigned short* __restrict__ Gsc,
    const double* __restrict__ Gd, int* __restrict__ cnt,
    unsigned short* __restrict__ list16, unsigned char* __restrict__ vbyte)
{
    __shared__ __align__(16) unsigned short hb[64 * 360];  // 46080 B
    __shared__ int vr[64], rs[64];
    __shared__ int flagl[64];
    __shared__ int nflag;
    __shared__ int lcnt[NR], lbase[NR];

    int tid = threadIdx.x;
    int rowbase = blockIdx.x * 64;
    if (tid == 0) nflag = 0;
    if (tid < NR) lcnt[tid] = 0;

    // ---- stage: 4800 float4, coalesced; bf16 into [seg0|seg1|seg2] stride 360 ----
    const float4* src4 = (const float4*)(hidden + (size_t)rowbase * 300);
#pragma unroll
    for (int kk = 0; kk < 19; ++kk) {
        int idx = tid + kk * 256;
        if (idx < 4800) {
            int row = idx / 75, c4 = idx - row * 75;
            float4 v = src4[idx];
            int cg = c4 * 4, seg = cg / 100, dd = cg - seg * 100;
            ushort4 o;
            o.x = f2bf(v.x); o.y = f2bf(v.y); o.z = f2bf(v.z); o.w = f2bf(v.w);
            *(ushort4*)&hb[row * 360 + seg * 112 + dd] = o;
        }
    }
    // zero pads: [100,112) [212,224) [324,360) per row = 15 ushort4
    for (int i = tid; i < 960; i += 256) {
        int row = i / 15, t = i - (i / 15) * 15;
        int off = (t < 3) ? (100 + t * 4) : (t < 6) ? (212 + (t - 3) * 4) : (324 + (t - 6) * 4);
        ushort4 z; z.x = z.y = z.z = z.w = 0;
        *(ushort4*)&hb[row * 360 + off] = z;
    }
    __syncthreads();

    int wave = tid >> 6, lane = tid & 63;
    int lr = lane & 15, lk = lane >> 4;
    int wrow0 = wave * 16;

    // ---- scores: 11 x mfma_16x16x32_bf16, then 16-lane top-2 butterfly ----
    {
        f32x4 sacc = (f32x4){0.f, 0.f, 0.f, 0.f};
#pragma unroll
        for (int ks = 0; ks < 11; ++ks) {
            bf16x8 a = *(const bf16x8*)&hb[(wrow0 + lr) * 360 + ks * 32 + lk * 8];
            bf16x8 g = *(const bf16x8*)&Gsc[(size_t)ks * 512 + lane * 8];
            sacc = __builtin_amdgcn_mfma_f32_16x16x32_bf16(a, g, sacc, 0, 0, 0);
        }
#pragma unroll
        for (int j = 0; j < 4; ++j) {
            float v1 = (lr < 8) ? sacc[j] : -3.4e38f;
            int i1 = lr;
            float v2 = -3.4e38f;
#pragma unroll
            for (int m = 1; m <= 8; m <<= 1) {
                float ov1 = __shfl_xor(v1, m);
                int oi1 = __shfl_xor(i1, m);
                float ov2 = __shfl_xor(v2, m);
                float nv2 = fmaxf(fminf(v1, ov1), fmaxf(v2, ov2));
                if (ov1 > v1 || (ov1 == v1 && oi1 < i1)) { v1 = ov1; i1 = oi1; }
                v2 = nv2;
            }
            if (lr == 0) {
                int row = wrow0 + lk * 4 + j;       // proven C layout: row=(l>>4)*4+j
                vr[row] = i1 & 1; rs[row] = i1 >> 1;
                if (v1 - v2 < 0.5f) { int s = atomicAdd(&nflag, 1); flagl[s] = row; }
            }
        }
    }
    __syncthreads();

    // ---- fp64 fixup for flagged rows (one wave per row) ----
    for (int f = wave; f < nflag; f += 4) {
        int row = flagl[f];
        const float* hr = hidden + (size_t)(rowbase + row) * 300;
        double a8[8];
#pragma unroll
        for (int p = 0; p < 8; ++p) a8[p] = 0.0;
        for (int e = lane; e < 300; e += 64) {
            double x = (double)hr[e];
#pragma unroll
            for (int p = 0; p < 8; ++p) a8[p] = fma(x, Gd[e * 8 + p], a8[p]);
        }
#pragma unroll
        for (int m = 1; m < 64; m <<= 1)
#pragma unroll
            for (int p = 0; p < 8; ++p) a8[p] += __shfl_xor(a8[p], m);
        if (lane == 0) {
            double bv = a8[0]; int best = 0;
#pragma unroll
            for (int p = 1; p < 8; ++p) if (a8[p] > bv) { bv = a8[p]; best = p; }
            vr[row] = best & 1; rs[row] = best >> 1;
        }
    }
    __syncthreads();

    // ---- proven bucket-atomic compaction ----
    int pos = 0;
    if (tid < 64) pos = atomicAdd(&lcnt[rs[tid]], 1);
    __syncthreads();
    if (tid < NR) lbase[tid] = atomicAdd(&cnt[tid], lcnt[tid]);
    __syncthreads();
    if (tid < 64) {
        vbyte[rowbase + tid] = (unsigned char)vr[tid];
        list16[rs[tid] * B_TOTAL + lbase[rs[tid]] + pos] = (unsigned short)(rowbase + tid);
    }
}

// ---------------- kernel 2: bucketed bf16-MFMA MLP (R18-proven v3, ~15us) ----------------
__global__ __launch_bounds__(256) void k2_mlp(
    const float* __restrict__ hidden,
    const unsigned short* __restrict__ W1f, const unsigned short* __restrict__ W2f,
    const int* __restrict__ cnt, const unsigned short* __restrict__ list16,
    const unsigned char* __restrict__ vbyte, float* __restrict__ out)
{
    int r = blockIdx.y;
    int nb = cnt[r];
    int m0 = blockIdx.x * 64;
    if (m0 >= nb) return;
    int me = nb - m0; if (me > 64) me = 64;

    __shared__ __align__(16) unsigned short shbuf[64 * 232]; // X [64][232]; C1 overlay [64][136]
    __shared__ int ent[64];

    int tid = threadIdx.x;
    int wave = tid >> 6, lane = tid & 63;
    int lr = lane & 15, lk = lane >> 4;
    int wrow0 = wave * 16;

    if (tid < 64) {
        int idx = m0 + tid; if (idx > nb - 1) idx = nb - 1;
        int b = list16[r * B_TOTAL + idx];
        int v = vbyte[b];
        ent[tid] = (b << 1) | v;
    }
    __syncthreads();

    // stage X: thread = (e, h, t): e=tid>>2 row, h=(tid>>1)&1 seg-half,
    // t=tid&1 sub-half. 13 consecutive float4 batched into regs.
    {
        int e = tid >> 2, hh = (tid >> 1) & 1, t = tid & 1;
        int en = ent[e];
        int b = en >> 1, v = en & 1;
        int seg = hh ? (1 - v) : v;
        int q0 = t * 12;   // 0..12 / 12..24 (chunk 12 written twice, same value)
        const float4* src = (const float4*)(hidden + (size_t)b * 300 + seg * 100) + q0;
        float4 hv[13];
#pragma unroll
        for (int u = 0; u < 13; ++u) hv[u] = src[u];
#pragma unroll
        for (int u = 0; u < 13; ++u) {
            ushort4 o;
            o.x = f2bf(hv[u].x); o.y = f2bf(hv[u].y);
            o.z = f2bf(hv[u].z); o.w = f2bf(hv[u].w);
            *(ushort4*)&shbuf[e * 232 + (hh * 25 + q0 + u) * 4] = o;
        }
    }
    // zero-pad k = [200,232) fully: 4 bf16x8 chunks per row (NaN-laundering
    // hazard: stale LDS * 0-weight = NaN -> relu -> zeroed rows).
    {
        int row = tid >> 2, part = tid & 3;
        bf16x8 z = {0, 0, 0, 0, 0, 0, 0, 0};
        *(bf16x8*)&shbuf[row * 232 + 200 + part * 8] = z;
    }
    __syncthreads();

    // ---- GEMM1 ----
    const unsigned short* W1f_r = W1f + (size_t)r * 28672;
    f32x4 acc1[8];
#pragma unroll
    for (int n = 0; n < 8; ++n) acc1[n] = (f32x4){0.f, 0.f, 0.f, 0.f};

#pragma unroll
    for (int ks = 0; ks < 7; ++ks) {
        bf16x8 a0 = *(const bf16x8*)&shbuf[(wrow0 + lr) * 232 + ks * 32 + lk * 8];
#pragma unroll
        for (int n = 0; n < 8; ++n) {
            bf16x8 bfr = *(const bf16x8*)&W1f_r[(size_t)(ks * 8 + n) * 512 + lane * 8];
            acc1[n] = __builtin_amdgcn_mfma_f32_16x16x32_bf16(a0, bfr, acc1[n], 0, 0, 0);
        }
    }

    __syncthreads();  // all waves done reading X before overlay

    // relu -> bf16 -> C1 transpose-store: row=wrow0+(lane>>4)*4+j, col=n*16+(lane&15)
#pragma unroll
    for (int n = 0; n < 8; ++n)
#pragma unroll
        for (int j = 0; j < 4; ++j) {
            float v = fmaxf(acc1[n][j], 0.f);
            int row = wrow0 + lk * 4 + j;
            shbuf[row * 136 + n * 16 + lr] = f2bf(v);
        }
    __syncthreads();

    // ---- GEMM2 ----
    const unsigned short* W2f_r = W2f + (size_t)r * 14336;
    f32x4 acc2[7];
#pragma unroll
    for (int n = 0; n < 7; ++n) acc2[n] = (f32x4){0.f, 0.f, 0.f, 0.f};

#pragma unroll
    for (int ks = 0; ks < 4; ++ks) {
        bf16x8 a0 = *(const bf16x8*)&shbuf[(wrow0 + lr) * 136 + ks * 32 + lk * 8];
#pragma unroll
        for (int n = 0; n < 7; ++n) {
            bf16x8 bfr = *(const bf16x8*)&W2f_r[(size_t)(ks * 7 + n) * 512 + lane * 8];
            acc2[n] = __builtin_amdgcn_mfma_f32_16x16x32_bf16(a0, bfr, acc2[n], 0, 0, 0);
        }
    }

    // scatter-store
#pragma unroll
    for (int n = 0; n < 7; ++n) {
        int col = n * 16 + lr;
        if (col < VD) {
#pragma unroll
            for (int j = 0; j < 4; ++j) {
                int e = wrow0 + lk * 4 + j;
                if (e < me) {
                    int b = ent[e] >> 1;
                    out[(size_t)b * VD + col] = acc2[n][j];
                }
            }
        }
    }
}

extern "C" void kernel_launch(void* const* d_in, const int* in_sizes, int n_in,
                              void* d_out, int out_size, void* d_ws, size_t ws_size,
                              hipStream_t stream) {
    (void)in_sizes; (void)n_in; (void)out_size; (void)ws_size;
    const float* hidden   = (const float*)d_in[0];
    const float* rule_emb = (const float*)d_in[1];
    const float* Wq       = (const float*)d_in[2];
    const float* bq       = (const float*)d_in[3];
    const float* Wk       = (const float*)d_in[4];
    const float* W1       = (const float*)d_in[5];
    const float* W2       = (const float*)d_in[6];
    float* out = (float*)d_out;

    char* ws = (char*)d_ws;
    double* Gd             = (double*)(ws + WS_GD);
    unsigned short* Gsc    = (unsigned short*)(ws + WS_GSC);
    int* cnt               = (int*)(ws + WS_CNT);
    unsigned short* list16 = (unsigned short*)(ws + WS_LIST);
    unsigned char* vbyte   = (unsigned char*)(ws + WS_VB);
    unsigned short* W1f    = (unsigned short*)(ws + WS_W1F);
    unsigned short* W2f    = (unsigned short*)(ws + WS_W2F);

    k0_prep<<<1, 256, 0, stream>>>(rule_emb, Wq, bq, Wk, Gd, Gsc, cnt);
    k0_wfrag<<<672, 256, 0, stream>>>(W1, W2, W1f, W2f);
    k1_select<<<1024, 256, 0, stream>>>(hidden, Gsc, Gd, cnt, list16, vbyte);
    k2_mlp<<<dim3(1024, NR), 256, 0, stream>>>(hidden, W1f, W2f, cnt, list16, vbyte, out);
}